// Round 2
// baseline (165.866 us; speedup 1.0000x reference)
//
#include <hip/hip_runtime.h>
#include <math.h>

#define L_   8192
#define D_   512
#define E_   8
#define DE_  4096        // D_*E_
#define C_   256         // number of L-chunks
#define LC_  32          // chunk length = L_/C_
#define NF4_ (LC_ * D_ / 4)   // f4 elements in a full-width chunk tile = 4096 (64 KB)
#define P2B_ 64          // pass2 block size

typedef float f4_t __attribute__((ext_vector_type(4)));

__device__ __forceinline__ float sigmoidf_(float v) {
    return 1.0f / (1.0f + expf(-v));
}

// ---------------------------------------------------------------------------
// Pass 1: block = one full chunk (all 512 d, all 8 e). 512 threads.
// Stage the 32x512 x-tile (64 KB) with a pure linear copy, then compute the
// chunk-local contribution (zero inbound state) for 2 f4 chain-groups per
// thread:  group A = chains [4t..4t+4), group B = chains [2048+4t..+4).
// Both groups share the same e-block (t&1), so only 4 (a,b) pairs per thread.
// ---------------------------------------------------------------------------
__global__ __launch_bounds__(512) void ema_pass1(const float* __restrict__ x,
                                                 const float* __restrict__ ld,
                                                 float* __restrict__ contrib) {
    __shared__ f4_t tile[NF4_];
    const int c = blockIdx.x;
    const int t = threadIdx.x;

    // linear 64 KB stage: tile == x[c*32 .. c*32+32)[0..512)
    const f4_t* xg = (const f4_t*)(x + (size_t)c * LC_ * D_);
#pragma unroll
    for (int k = 0; k < 8; ++k) tile[t + 512 * k] = xg[t + 512 * k];

    const int dA = t >> 1;            // 0..255
    const int dB = 256 + (t >> 1);    // 256..511
    const int eb = (t & 1) << 2;      // e-block 0 or 4
    float a[4], b[4];
#pragma unroll
    for (int e = 0; e < 4; ++e) { a[e] = sigmoidf_(ld[eb + e]); b[e] = 1.0f - a[e]; }

    __syncthreads();

    const float* tl = (const float*)tile;
    float sA[4] = {0.f, 0.f, 0.f, 0.f};
    float sB[4] = {0.f, 0.f, 0.f, 0.f};
#pragma unroll
    for (int r = 0; r < LC_; ++r) {
        const float xA = tl[r * D_ + dA];   // 2-lane broadcast, conflict-free
        const float xB = tl[r * D_ + dB];
#pragma unroll
        for (int e = 0; e < 4; ++e) {
            sA[e] = fmaf(b[e], sA[e], a[e] * xA);
            sB[e] = fmaf(b[e], sB[e], a[e] * xB);
        }
    }
    f4_t rA = {sA[0], sA[1], sA[2], sA[3]};
    f4_t rB = {sB[0], sB[1], sB[2], sB[3]};
    *(f4_t*)(contrib + (size_t)c * DE_ + 4 * t)        = rA;   // dense 1KB/wave
    *(f4_t*)(contrib + (size_t)c * DE_ + 2048 + 4 * t) = rB;
}

// ---------------------------------------------------------------------------
// Pass 2: per chain (d,e), scan the 256 chunk contributions.
// states[0] = x[0,d]; states[c+1] = (1-a)^LC * states[c] + contrib[c]
// states has C_+1 rows so the last store needs no guard. Unchanged from r1.
// ---------------------------------------------------------------------------
__global__ __launch_bounds__(P2B_) void ema_pass2(const float* __restrict__ x,
                                                  const float* __restrict__ ld,
                                                  const float* __restrict__ contrib,
                                                  float* __restrict__ states) {
    const int chain = blockIdx.x * P2B_ + threadIdx.x;   // 0..4095
    const int d = chain >> 3;
    const int e = chain & 7;
    const float a = sigmoidf_(ld[e]);
    float B = 1.0f - a;
#pragma unroll
    for (int k = 0; k < 5; ++k) B *= B;   // (1-a)^32

    float cb[2][32];
#pragma unroll
    for (int j = 0; j < 32; ++j) cb[0][j] = contrib[(size_t)j * DE_ + chain];

    float s = x[d];                        // initial carry = x[0, d]
    states[chain] = s;

#pragma unroll
    for (int gr = 0; gr < C_ / 32; ++gr) {
        if (gr + 1 < C_ / 32) {
#pragma unroll
            for (int j = 0; j < 32; ++j)
                cb[(gr + 1) & 1][j] = contrib[(size_t)((gr + 1) * 32 + j) * DE_ + chain];
        }
#pragma unroll
        for (int j = 0; j < 32; ++j) {
            s = fmaf(B, s, cb[gr & 1][j]);
            states[(size_t)(gr * 32 + j + 1) * DE_ + chain] = s;
        }
    }
}

// ---------------------------------------------------------------------------
// Pass 3: block = one full chunk. Replay from the correct inbound state and
// stream the output as ONE CONTIGUOUS 512 KB LINEAR WRITE per block:
// each output row (16 KB) is written as 16 dense 1 KB wave-stores (2 per
// thread at +0 / +8 KB), and a per-row __syncthreads() keeps the 8 waves'
// write fronts merged so rows retire in order -> fill-like DRAM locality.
// ---------------------------------------------------------------------------
__global__ __launch_bounds__(512) void ema_pass3(const float* __restrict__ x,
                                                 const float* __restrict__ ld,
                                                 const float* __restrict__ states,
                                                 float* __restrict__ out) {
    __shared__ f4_t tile[NF4_];
    const int c = blockIdx.x;
    const int t = threadIdx.x;

    const f4_t* xg = (const f4_t*)(x + (size_t)c * LC_ * D_);
#pragma unroll
    for (int k = 0; k < 8; ++k) tile[t + 512 * k] = xg[t + 512 * k];

    const int dA = t >> 1;
    const int dB = 256 + (t >> 1);
    const int eb = (t & 1) << 2;
    float a[4], b[4];
#pragma unroll
    for (int e = 0; e < 4; ++e) { a[e] = sigmoidf_(ld[eb + e]); b[e] = 1.0f - a[e]; }

    f4_t yA = *(const f4_t*)(states + (size_t)c * DE_ + 4 * t);
    f4_t yB = *(const f4_t*)(states + (size_t)c * DE_ + 2048 + 4 * t);
    float* op = out + (size_t)c * LC_ * DE_ + 4 * t;

    __syncthreads();

    const float* tl = (const float*)tile;
    for (int r = 0; r < LC_; ++r) {
        const float xA = tl[r * D_ + dA];
        const float xB = tl[r * D_ + dB];
        yA.x = fmaf(b[0], yA.x, a[0] * xA);
        yA.y = fmaf(b[1], yA.y, a[1] * xA);
        yA.z = fmaf(b[2], yA.z, a[2] * xA);
        yA.w = fmaf(b[3], yA.w, a[3] * xA);
        yB.x = fmaf(b[0], yB.x, a[0] * xB);
        yB.y = fmaf(b[1], yB.y, a[1] * xB);
        yB.z = fmaf(b[2], yB.z, a[2] * xB);
        yB.w = fmaf(b[3], yB.w, a[3] * xB);
        __builtin_nontemporal_store(yA, (f4_t*)(op + (size_t)r * DE_));
        __builtin_nontemporal_store(yB, (f4_t*)(op + (size_t)r * DE_ + 2048));
        __syncthreads();   // keep the 8 wave write-fronts merged: rows retire in order
    }
}

// Fallback if workspace is too small: one thread per chain, full serial scan.
__global__ __launch_bounds__(256) void ema_naive(const float* __restrict__ x,
                                                 const float* __restrict__ ld,
                                                 float* __restrict__ out) {
    const int chain = blockIdx.x * 256 + threadIdx.x;  // 0..4095
    const int d = chain >> 3;
    const int e = chain & 7;
    const float a = sigmoidf_(ld[e]);
    const float b = 1.0f - a;
    float y = x[d];
    for (int l = 0; l < L_; ++l) {
        y = fmaf(b, y, a * x[(size_t)l * D_ + d]);
        out[(size_t)l * DE_ + chain] = y;
    }
}

extern "C" void kernel_launch(void* const* d_in, const int* in_sizes, int n_in,
                              void* d_out, int out_size, void* d_ws, size_t ws_size,
                              hipStream_t stream) {
    const float* x  = (const float*)d_in[0];
    const float* ld = (const float*)d_in[1];
    float* out = (float*)d_out;

    // contrib: C_ rows; states: C_+1 rows (extra row = unguarded last store)
    const size_t need = (size_t)(2 * C_ + 1) * DE_ * sizeof(float);
    if (ws_size >= need) {
        float* contrib = (float*)d_ws;
        float* states  = contrib + (size_t)C_ * DE_;
        ema_pass1<<<C_, 512, 0, stream>>>(x, ld, contrib);
        ema_pass2<<<DE_ / P2B_, P2B_, 0, stream>>>(x, ld, contrib, states);
        ema_pass3<<<C_, 512, 0, stream>>>(x, ld, states, out);
    } else {
        ema_naive<<<DE_ / 256, 256, 0, stream>>>(x, ld, out);
    }
}

// Round 3
// 158.895 us; speedup vs baseline: 1.0439x; 1.0439x over previous
//
#include <hip/hip_runtime.h>
#include <math.h>

#define L_   8192
#define D_   512
#define E_   8
#define DE_  4096        // D_*E_
#define C_   256         // number of L-chunks
#define LC_  32          // chunk length = L_/C_
#define TD_  128         // d-span per block (D_/4)
#define NF4_ (LC_ * TD_ / 4)   // f4 elements in an LDS tile = 1024 (16 KB)
#define P2B_ 64          // pass2 block size

typedef float f4_t __attribute__((ext_vector_type(4)));

__device__ __forceinline__ float sigmoidf_(float v) {
    return 1.0f / (1.0f + expf(-v));
}

// ---------------------------------------------------------------------------
// Pass 1: per (chunk c, d-quarter q) block. Stage the 32x128 x-tile into LDS
// once, then compute the chunk-local contribution with zero inbound state:
//   s[e] = sum_i b^(LC-1-i) * a * x[c*LC+i, d]
// Identical to round 1.
// ---------------------------------------------------------------------------
__global__ __launch_bounds__(256) void ema_pass1(const float* __restrict__ x,
                                                 const float* __restrict__ ld,
                                                 float* __restrict__ contrib) {
    __shared__ f4_t tile[NF4_];          // [32 rows][32 f4] = [32][128 floats]
    const int c = blockIdx.x >> 2;
    const int q = blockIdx.x & 3;
    const int t = threadIdx.x;

    const f4_t* xg = (const f4_t*)(x + (size_t)c * LC_ * D_ + q * TD_);
#pragma unroll
    for (int k = 0; k < 4; ++k) {
        const int i = t + 256 * k;                       // 0..1023
        tile[i] = xg[(size_t)(i >> 5) * (D_ / 4) + (i & 31)];
    }

    const int g  = (q << 8) + t;          // global group 0..1023
    const int dl = t >> 1;                // local d in [0,128)
    const int eb = (g & 1) << 2;          // e-block 0 or 4
    float a[4], b[4];
#pragma unroll
    for (int e = 0; e < 4; ++e) { a[e] = sigmoidf_(ld[eb + e]); b[e] = 1.0f - a[e]; }

    __syncthreads();

    const float* tl = (const float*)tile;
    float s[4] = {0.f, 0.f, 0.f, 0.f};
#pragma unroll
    for (int r = 0; r < LC_; ++r) {
        const float xv = tl[r * TD_ + dl];   // 2-lane broadcast, conflict-free
#pragma unroll
        for (int e = 0; e < 4; ++e) s[e] = fmaf(b[e], s[e], a[e] * xv);
    }
    f4_t rr = {s[0], s[1], s[2], s[3]};
    *(f4_t*)(contrib + (size_t)c * DE_ + 4 * g) = rr;
}

// ---------------------------------------------------------------------------
// Pass 2: per chain (d,e), scan the 256 chunk contributions. Unchanged.
// states[0] = x[0,d]; states[c+1] = (1-a)^LC * states[c] + contrib[c]
// ---------------------------------------------------------------------------
__global__ __launch_bounds__(P2B_) void ema_pass2(const float* __restrict__ x,
                                                  const float* __restrict__ ld,
                                                  const float* __restrict__ contrib,
                                                  float* __restrict__ states) {
    const int chain = blockIdx.x * P2B_ + threadIdx.x;   // 0..4095
    const int d = chain >> 3;
    const int e = chain & 7;
    const float a = sigmoidf_(ld[e]);
    float B = 1.0f - a;
#pragma unroll
    for (int k = 0; k < 5; ++k) B *= B;   // (1-a)^32

    float cb[2][32];
#pragma unroll
    for (int j = 0; j < 32; ++j) cb[0][j] = contrib[(size_t)j * DE_ + chain];

    float s = x[d];                        // initial carry = x[0, d]
    states[chain] = s;

#pragma unroll
    for (int gr = 0; gr < C_ / 32; ++gr) {
        if (gr + 1 < C_ / 32) {
#pragma unroll
            for (int j = 0; j < 32; ++j)
                cb[(gr + 1) & 1][j] = contrib[(size_t)((gr + 1) * 32 + j) * DE_ + chain];
        }
#pragma unroll
        for (int j = 0; j < 32; ++j) {
            s = fmaf(B, s, cb[gr & 1][j]);
            states[(size_t)(gr * 32 + j + 1) * DE_ + chain] = s;
        }
    }
}

// ---------------------------------------------------------------------------
// Pass 3: replay each chunk from its correct inbound state, stream output.
// THE ONLY THEORY-BEARING CHANGE THIS ROUND: plain cached f4 stores instead
// of __builtin_nontemporal_store. out (134 MB) fits the 256 MB Infinity
// Cache; cached stores retire at L2/L3 rate and drain to DRAM after the
// timed window, instead of each nt store serializing to HBM.
// ---------------------------------------------------------------------------
__global__ __launch_bounds__(256) void ema_pass3(const float* __restrict__ x,
                                                 const float* __restrict__ ld,
                                                 const float* __restrict__ states,
                                                 float* __restrict__ out) {
    __shared__ f4_t tile[NF4_];
    const int c = blockIdx.x >> 2;
    const int q = blockIdx.x & 3;
    const int t = threadIdx.x;

    const f4_t* xg = (const f4_t*)(x + (size_t)c * LC_ * D_ + q * TD_);
#pragma unroll
    for (int k = 0; k < 4; ++k) {
        const int i = t + 256 * k;
        tile[i] = xg[(size_t)(i >> 5) * (D_ / 4) + (i & 31)];
    }

    const int g  = (q << 8) + t;
    const int dl = t >> 1;
    const int eb = (g & 1) << 2;
    float a[4], b[4];
#pragma unroll
    for (int e = 0; e < 4; ++e) { a[e] = sigmoidf_(ld[eb + e]); b[e] = 1.0f - a[e]; }

    f4_t y = *(const f4_t*)(states + (size_t)c * DE_ + 4 * g);
    float* op = out + (size_t)c * LC_ * DE_ + 4 * g;

    __syncthreads();

    const float* tl = (const float*)tile;
#pragma unroll
    for (int r = 0; r < LC_; ++r) {
        const float xv = tl[r * TD_ + dl];
        y.x = fmaf(b[0], y.x, a[0] * xv);
        y.y = fmaf(b[1], y.y, a[1] * xv);
        y.z = fmaf(b[2], y.z, a[2] * xv);
        y.w = fmaf(b[3], y.w, a[3] * xv);
        *(f4_t*)(op + (size_t)r * DE_) = y;   // plain cached store (was nt)
    }
}

// Fallback if workspace is too small: one thread per chain, full serial scan.
__global__ __launch_bounds__(256) void ema_naive(const float* __restrict__ x,
                                                 const float* __restrict__ ld,
                                                 float* __restrict__ out) {
    const int chain = blockIdx.x * 256 + threadIdx.x;  // 0..4095
    const int d = chain >> 3;
    const int e = chain & 7;
    const float a = sigmoidf_(ld[e]);
    const float b = 1.0f - a;
    float y = x[d];
    for (int l = 0; l < L_; ++l) {
        y = fmaf(b, y, a * x[(size_t)l * D_ + d]);
        out[(size_t)l * DE_ + chain] = y;
    }
}

extern "C" void kernel_launch(void* const* d_in, const int* in_sizes, int n_in,
                              void* d_out, int out_size, void* d_ws, size_t ws_size,
                              hipStream_t stream) {
    const float* x  = (const float*)d_in[0];
    const float* ld = (const float*)d_in[1];
    float* out = (float*)d_out;

    // contrib: C_ rows; states: C_+1 rows (extra row = unguarded last store)
    const size_t need = (size_t)(2 * C_ + 1) * DE_ * sizeof(float);
    if (ws_size >= need) {
        float* contrib = (float*)d_ws;
        float* states  = contrib + (size_t)C_ * DE_;
        ema_pass1<<<C_ * 4, 256, 0, stream>>>(x, ld, contrib);
        ema_pass2<<<DE_ / P2B_, P2B_, 0, stream>>>(x, ld, contrib, states);
        ema_pass3<<<C_ * 4, 256, 0, stream>>>(x, ld, states, out);
    } else {
        ema_naive<<<DE_ / 256, 256, 0, stream>>>(x, ld, out);
    }
}